// Round 1
// baseline (811.794 us; speedup 1.0000x reference)
//
#include <hip/hip_runtime.h>
#include <hip/hip_bf16.h>
#include <math.h>

#define LTOT   4096
#define EDIM   64
#define NMODES 64
#define BH     256      // B*H = 32*8
#define LSPLIT 4
#define TWO_PI 6.28318530717958647692f

// ---------- K0a: trig tables, layout [l][k] (for stage1) ----------
__global__ void k_tables_lk(const int* __restrict__ index,
                            float* __restrict__ cosT, float* __restrict__ sinT) {
    int l = blockIdx.x;              // 0..4095
    int k = threadIdx.x;             // 0..63
    int f = index[k];                // frequency in [0, 2048)
    int m = (f * l) & (LTOT - 1);    // exact angle reduction
    float th = (float)m * (TWO_PI / (float)LTOT);
    float s, c;
    sincosf(th, &s, &c);
    cosT[l * NMODES + k] = c;
    sinT[l * NMODES + k] = s;
}

// ---------- K0b: trig tables, layout [k][l] (for stage3) ----------
__global__ void k_tables_kl(const int* __restrict__ index,
                            float* __restrict__ cosTT, float* __restrict__ sinTT) {
    int k = blockIdx.x;              // 0..63
    int f = index[k];
    for (int l = threadIdx.x; l < LTOT; l += blockDim.x) {
        int m = (f * l) & (LTOT - 1);
        float th = (float)m * (TWO_PI / (float)LTOT);
        float s, c;
        sincosf(th, &s, &c);
        cosTT[(size_t)k * LTOT + l] = c;
        sinTT[(size_t)k * LTOT + l] = s;
    }
}

// ---------- K0c: reorder weights to [k][e][o] float2 ----------
__global__ void k_wt(const float* __restrict__ w, float2* __restrict__ wt) {
    int k = blockIdx.x;              // 0..63
    int e = blockIdx.y;              // 0..63
    int o = threadIdx.x;             // 0..63
    const float* p = w + (((size_t)e * EDIM + o) * NMODES + k) * 2;
    wt[((size_t)k * EDIM + e) * EDIM + o] = make_float2(p[0], p[1]);
}

// ---------- K1: forward sparse DFT: X[k,e] = sum_l x[l,e] * e^{-i th} ----------
// grid = BH*LSPLIT blocks, 256 threads. Each block does 1/LSPLIT of L, partial sums.
__global__ __launch_bounds__(256) void k_stage1(const float* __restrict__ x,
                                                const float* __restrict__ cosT,
                                                const float* __restrict__ sinT,
                                                float2* __restrict__ Xp) {
    int bh   = blockIdx.x >> 2;      // LSPLIT = 4
    int part = blockIdx.x & 3;
    const float* xb = x + (size_t)bh * LTOT * EDIM;

    __shared__ float xs[64 * 64];
    __shared__ float cs[64 * 64];
    __shared__ float ss[64 * 64];

    int t  = threadIdx.x;
    int kg = t >> 4;                 // k = kg*4 + i
    int eg = t & 15;                 // e = eg*4 + j
    float accR[4][4] = {};
    float accI[4][4] = {};

    int lbase = part * (LTOT / LSPLIT);
    for (int c = 0; c < (LTOT / LSPLIT) / 64; ++c) {
        int l0 = lbase + c * 64;
        __syncthreads();
        const float4* xg = (const float4*)(xb + (size_t)l0 * EDIM);
        const float4* cg = (const float4*)(cosT + (size_t)l0 * NMODES);
        const float4* sg = (const float4*)(sinT + (size_t)l0 * NMODES);
        float4* xs4 = (float4*)xs; float4* cs4 = (float4*)cs; float4* ss4 = (float4*)ss;
        #pragma unroll
        for (int r = 0; r < 4; ++r) {
            xs4[t + r * 256] = xg[t + r * 256];
            cs4[t + r * 256] = cg[t + r * 256];
            ss4[t + r * 256] = sg[t + r * 256];
        }
        __syncthreads();
        #pragma unroll 4
        for (int l = 0; l < 64; ++l) {
            float4 xv = *(const float4*)&xs[l * 64 + eg * 4];
            float4 cv = *(const float4*)&cs[l * 64 + kg * 4];
            float4 sv = *(const float4*)&ss[l * 64 + kg * 4];
            float xa[4] = {xv.x, xv.y, xv.z, xv.w};
            float ca[4] = {cv.x, cv.y, cv.z, cv.w};
            float sa[4] = {sv.x, sv.y, sv.z, sv.w};
            #pragma unroll
            for (int i = 0; i < 4; ++i)
                #pragma unroll
                for (int j = 0; j < 4; ++j) {
                    accR[i][j] += ca[i] * xa[j];   // Re += x*cos
                    accI[i][j] -= sa[i] * xa[j];   // Im -= x*sin  (e^{-i th})
                }
        }
    }

    float2* Xb = Xp + ((size_t)part * BH + bh) * NMODES * EDIM;
    #pragma unroll
    for (int i = 0; i < 4; ++i)
        #pragma unroll
        for (int j = 0; j < 4; ++j)
            Xb[(kg * 4 + i) * EDIM + eg * 4 + j] = make_float2(accR[i][j], accI[i][j]);
}

// ---------- K2: per-mode complex channel mix + irfft coefficient prep ----------
// grid = BH*64 blocks (bh, k), 64 threads (o).
__global__ __launch_bounds__(64) void k_stage2(const float2* __restrict__ Xp,
                                               const float2* __restrict__ wt,
                                               const int* __restrict__ index,
                                               float* __restrict__ A,
                                               float* __restrict__ Bq) {
    int bh = blockIdx.x >> 6;
    int k  = blockIdx.x & 63;
    int o  = threadIdx.x;

    __shared__ float2 Xs[EDIM];
    {
        float2 v = make_float2(0.f, 0.f);
        #pragma unroll
        for (int p = 0; p < LSPLIT; ++p) {
            float2 u = Xp[(((size_t)p * BH + bh) * NMODES + k) * EDIM + o];
            v.x += u.x; v.y += u.y;
        }
        Xs[o] = v;
    }
    __syncthreads();

    const float2* wk = wt + (size_t)k * EDIM * EDIM;
    float aR = 0.f, aI = 0.f;
    #pragma unroll 8
    for (int e = 0; e < EDIM; ++e) {
        float2 xv = Xs[e];
        float2 wv = wk[e * EDIM + o];
        aR += xv.x * wv.x - xv.y * wv.y;   // complex multiply-accumulate
        aI += xv.x * wv.y + xv.y * wv.x;
    }

    int f = index[k];
    float cc = (f == 0 ? 1.0f : 2.0f) * (1.0f / (float)LTOT);
    size_t off = ((size_t)bh * NMODES + k) * EDIM + o;
    A[off]  = cc * aR;
    Bq[off] = (f == 0) ? 0.0f : -cc * aI;  // irfft drops Im at DC
}

// ---------- K3: inverse sparse DFT: y[l,o] = sum_k A*cos + Bq*sin ----------
// grid = BH*64 blocks (bh, l-chunk of 64), 256 threads.
__global__ __launch_bounds__(256) void k_stage3(const float* __restrict__ A,
                                                const float* __restrict__ Bq,
                                                const float* __restrict__ cosTT,
                                                const float* __restrict__ sinTT,
                                                float* __restrict__ y) {
    int bh = blockIdx.x >> 6;
    int lc = blockIdx.x & 63;
    int l0 = lc * 64;

    __shared__ float As[4096], Bs[4096], Cs[4096], Ss[4096];  // 64 KB
    int t = threadIdx.x;

    const float4* Ag = (const float4*)(A  + (size_t)bh * 4096);
    const float4* Bg = (const float4*)(Bq + (size_t)bh * 4096);
    #pragma unroll
    for (int r = 0; r < 4; ++r) {
        ((float4*)As)[t + r * 256] = Ag[t + r * 256];
        ((float4*)Bs)[t + r * 256] = Bg[t + r * 256];
    }
    #pragma unroll
    for (int r = 0; r < 4; ++r) {
        int idx = t + r * 256;            // float4 index into [64k][16]
        int k = idx >> 4;
        int j = idx & 15;
        ((float4*)Cs)[idx] = ((const float4*)(cosTT + (size_t)k * LTOT + l0))[j];
        ((float4*)Ss)[idx] = ((const float4*)(sinTT + (size_t)k * LTOT + l0))[j];
    }
    __syncthreads();

    int lg = t >> 4, og = t & 15;
    float acc[4][4] = {};
    #pragma unroll 2
    for (int k = 0; k < 64; ++k) {
        float4 cv = *(const float4*)&Cs[k * 64 + lg * 4];
        float4 sv = *(const float4*)&Ss[k * 64 + lg * 4];
        float4 av = *(const float4*)&As[k * 64 + og * 4];
        float4 bv = *(const float4*)&Bs[k * 64 + og * 4];
        float ca[4] = {cv.x, cv.y, cv.z, cv.w};
        float sa[4] = {sv.x, sv.y, sv.z, sv.w};
        float aa[4] = {av.x, av.y, av.z, av.w};
        float ba[4] = {bv.x, bv.y, bv.z, bv.w};
        #pragma unroll
        for (int i = 0; i < 4; ++i)
            #pragma unroll
            for (int j = 0; j < 4; ++j)
                acc[i][j] += ca[i] * aa[j] + sa[i] * ba[j];
    }

    float* yb = y + ((size_t)bh * LTOT + l0) * EDIM;
    #pragma unroll
    for (int i = 0; i < 4; ++i) {
        *(float4*)&yb[(size_t)(lg * 4 + i) * EDIM + og * 4] =
            make_float4(acc[i][0], acc[i][1], acc[i][2], acc[i][3]);
    }
}

extern "C" void kernel_launch(void* const* d_in, const int* in_sizes, int n_in,
                              void* d_out, int out_size, void* d_ws, size_t ws_size,
                              hipStream_t stream) {
    const float* x     = (const float*)d_in[0];
    const float* w     = (const float*)d_in[1];
    const int*   index = (const int*)d_in[2];
    float* y  = (float*)d_out;
    float* ws = (float*)d_ws;

    // ws layout (float offsets)
    float*  cosT  = ws;                       //  1 MB  [l][k]
    float*  sinT  = ws + 262144;              //  1 MB
    float*  cosTT = ws + 524288;              //  1 MB  [k][l]
    float*  sinTT = ws + 786432;              //  1 MB
    float2* wt    = (float2*)(ws + 1048576);  //  2 MB  [k][e][o] complex
    float2* Xp    = (float2*)(ws + 1572864);  // 32 MB  [part][bh][k][e] complex
    float*  A     = ws + 9961472;             //  4 MB  [bh][k][o]
    float*  Bq    = ws + 11010048;            //  4 MB

    hipLaunchKernelGGL(k_tables_lk, dim3(LTOT), dim3(NMODES), 0, stream, index, cosT, sinT);
    hipLaunchKernelGGL(k_tables_kl, dim3(NMODES), dim3(256), 0, stream, index, cosTT, sinTT);
    hipLaunchKernelGGL(k_wt, dim3(NMODES, EDIM), dim3(EDIM), 0, stream, w, wt);
    hipLaunchKernelGGL(k_stage1, dim3(BH * LSPLIT), dim3(256), 0, stream, x, cosT, sinT, Xp);
    hipLaunchKernelGGL(k_stage2, dim3(BH * 64), dim3(64), 0, stream, Xp, wt, index, A, Bq);
    hipLaunchKernelGGL(k_stage3, dim3(BH * 64), dim3(256), 0, stream, A, Bq, cosTT, sinTT, y);
}

// Round 2
// 203.099 us; speedup vs baseline: 3.9970x; 3.9970x over previous
//
#include <hip/hip_runtime.h>
#include <hip/hip_bf16.h>
#include <math.h>

#define LTOT   4096
#define EDIM   64
#define NMODES 64
#define BH     256
#define TWO_PI 6.28318530717958647692f

typedef float f32x4 __attribute__((ext_vector_type(4)));
typedef short s16x8 __attribute__((ext_vector_type(8)));

__device__ inline unsigned short f2bf(float f) {
    unsigned u = __builtin_bit_cast(unsigned, f);
    u += 0x7fff + ((u >> 16) & 1);           // round-to-nearest-even
    return (unsigned short)(u >> 16);
}
__device__ inline unsigned packbf(float lo, float hi) {
    return (unsigned)f2bf(lo) | ((unsigned)f2bf(hi) << 16);
}

// ---------- Tables ----------
// Tm[m=128][l=4096] bf16: Tm[2k][l]=cos, Tm[2k+1][l]=-sin  (forward DFT)
__global__ void k_tab_m(const int* __restrict__ index, unsigned short* __restrict__ Tm) {
    int k = blockIdx.x;
    int f = index[k];
    for (int l = threadIdx.x; l < LTOT; l += blockDim.x) {
        int m = (f * l) & (LTOT - 1);
        float th = (float)m * (TWO_PI / (float)LTOT);
        float s, c; sincosf(th, &s, &c);
        Tm[(size_t)(2 * k) * LTOT + l]     = f2bf(c);
        Tm[(size_t)(2 * k + 1) * LTOT + l] = f2bf(-s);
    }
}
// Tt[l=4096][m=128] bf16: Tt[l][2k]=cos, Tt[l][2k+1]=sin  (inverse DFT)
__global__ void k_tab_t(const int* __restrict__ index, unsigned short* __restrict__ Tt) {
    int l = blockIdx.x * 4 + (threadIdx.x >> 6);
    int k = threadIdx.x & 63;
    int f = index[k];
    int m = (f * l) & (LTOT - 1);
    float th = (float)m * (TWO_PI / (float)LTOT);
    float s, c; sincosf(th, &s, &c);
    ((unsigned*)Tt)[l * 64 + k] = packbf(c, s);
}

// ---------- Stage 1: X[e][m] = sum_l xT[e][l] * T[l][m]  (MFMA bf16) ----------
// grid = BH*4 (bh, quarter-of-L partial), 256 threads (4 waves).
#define S1PITCH 72   // u16 pitch of xT rows (16B-aligned rows, low bank conflict)
__global__ __launch_bounds__(256) void k_stage1(const float* __restrict__ x,
                                                const unsigned short* __restrict__ Tm,
                                                float* __restrict__ Xp) {
    int bh = blockIdx.x >> 2, part = blockIdx.x & 3;
    const float* xb = x + (size_t)bh * LTOT * EDIM;
    __shared__ unsigned xT[64 * (S1PITCH / 2)];   // [e=64][72 bf16] as u32

    int t = threadIdx.x;
    int q = t & 15, lp = t >> 4;                  // loader role
    int lane = t & 63, wave = t >> 6;             // mfma role
    int r = lane & 15, kb8 = lane >> 4;
    int wbase = wave * 32;                        // mode-column base (32 per wave)

    f32x4 acc[4][2];
    #pragma unroll
    for (int i = 0; i < 4; ++i) { acc[i][0] = (f32x4)0.f; acc[i][1] = (f32x4)0.f; }

    for (int tile = 0; tile < 16; ++tile) {
        int l0 = part * 1024 + tile * 64;
        __syncthreads();
        const float* b0 = xb + (size_t)(l0 + 2 * lp) * EDIM + 4 * q;
        float4 a0 = *(const float4*)(b0);
        float4 a1 = *(const float4*)(b0 + EDIM);
        float4 a2 = *(const float4*)(b0 + 32 * EDIM);
        float4 a3 = *(const float4*)(b0 + 33 * EDIM);
        float A0[4] = {a0.x, a0.y, a0.z, a0.w};
        float A1[4] = {a1.x, a1.y, a1.z, a1.w};
        float A2[4] = {a2.x, a2.y, a2.z, a2.w};
        float A3[4] = {a3.x, a3.y, a3.z, a3.w};
        #pragma unroll
        for (int j = 0; j < 4; ++j) {
            int e = 4 * q + j;
            xT[e * (S1PITCH / 2) + lp]      = packbf(A0[j], A1[j]);   // l_off 2lp,2lp+1
            xT[e * (S1PITCH / 2) + lp + 16] = packbf(A2[j], A3[j]);   // l_off 2lp+32,+33
        }
        __syncthreads();
        #pragma unroll
        for (int kk = 0; kk < 2; ++kk) {
            s16x8 bf[2];
            #pragma unroll
            for (int ns = 0; ns < 2; ++ns) {
                int m = wbase + ns * 16 + r;
                bf[ns] = *(const s16x8*)(Tm + (size_t)m * LTOT + (l0 + kk * 32 + kb8 * 8));
            }
            #pragma unroll
            for (int es = 0; es < 4; ++es) {
                int e = es * 16 + r;
                s16x8 af = *(const s16x8*)((const unsigned short*)xT + e * S1PITCH + kk * 32 + kb8 * 8);
                #pragma unroll
                for (int ns = 0; ns < 2; ++ns)
                    acc[es][ns] = __builtin_amdgcn_mfma_f32_16x16x32_bf16(af, bf[ns], acc[es][ns], 0, 0, 0);
            }
        }
    }
    float* Xb = Xp + ((size_t)part * BH + bh) * (64 * 128);
    #pragma unroll
    for (int es = 0; es < 4; ++es)
        #pragma unroll
        for (int ns = 0; ns < 2; ++ns)
            #pragma unroll
            for (int g = 0; g < 4; ++g) {
                int e = es * 16 + kb8 * 4 + g;      // C/D: row=(lane>>4)*4+reg
                int m = wbase + ns * 16 + r;        //      col=lane&15
                Xb[e * 128 + m] = acc[es][ns][g];
            }
}

// ---------- Stage 2: mode mix (complex 64x64 per mode) + irfft coeff prep ----------
// grid = 128 (2 bh each), 512 threads. AB[bh][2k][o]=cc*Re, AB[bh][2k+1][o]=-cc*Im (0 at DC)
__global__ __launch_bounds__(512) void k_stage2(const float* __restrict__ Xp,
                                                const float2* __restrict__ w2,
                                                const int* __restrict__ index,
                                                unsigned short* __restrict__ AB) {
    int bh0 = blockIdx.x * 2;
    __shared__ float Xs[2][64 * 128];   // 64 KB
    int t = threadIdx.x;

    #pragma unroll
    for (int bhi = 0; bhi < 2; ++bhi) {
        f32x4 a[4];
        #pragma unroll
        for (int i = 0; i < 4; ++i) a[i] = (f32x4)0.f;
        #pragma unroll
        for (int p = 0; p < 4; ++p) {
            const f32x4* src = (const f32x4*)(Xp + ((size_t)p * BH + bh0 + bhi) * 8192);
            #pragma unroll
            for (int i = 0; i < 4; ++i) a[i] += src[t + i * 512];
        }
        f32x4* dst = (f32x4*)Xs[bhi];
        #pragma unroll
        for (int i = 0; i < 4; ++i) dst[t + i * 512] = a[i];
    }
    __syncthreads();

    int k = t & 63, og = t >> 6;     // og 0..7 -> 8 outputs each
    int f = index[k];
    float cc = (f == 0 ? 1.0f : 2.0f) / (float)LTOT;
    float aR[2][8] = {}, aI[2][8] = {};
    for (int e = 0; e < 64; ++e) {
        float2 X0 = *(const float2*)&Xs[0][e * 128 + 2 * k];
        float2 X1 = *(const float2*)&Xs[1][e * 128 + 2 * k];
        #pragma unroll
        for (int oi = 0; oi < 8; ++oi) {
            int o = og * 8 + oi;
            float2 wv = w2[((size_t)e * 64 + o) * 64 + k];   // w is [e][o][k] float2 natively
            aR[0][oi] += X0.x * wv.x - X0.y * wv.y;
            aI[0][oi] += X0.x * wv.y + X0.y * wv.x;
            aR[1][oi] += X1.x * wv.x - X1.y * wv.y;
            aI[1][oi] += X1.x * wv.y + X1.y * wv.x;
        }
    }
    #pragma unroll
    for (int bhi = 0; bhi < 2; ++bhi)
        #pragma unroll
        for (int oi = 0; oi < 8; ++oi) {
            int o = og * 8 + oi;
            size_t b = ((size_t)(bh0 + bhi) * 128 + 2 * k) * 64 + o;
            AB[b]      = f2bf(cc * aR[bhi][oi]);
            AB[b + 64] = (f == 0) ? (unsigned short)0 : f2bf(-cc * aI[bhi][oi]);
        }
}

// ---------- Stage 3: y[l][o] = sum_m Tt[l][m] * AB[m][o]  (MFMA bf16) ----------
// grid = BH*4 (bh, quarter of L), 256 threads (4 waves). B-frags register-cached.
#define S3PITCH 72
__global__ __launch_bounds__(256) void k_stage3(const unsigned short* __restrict__ Tt,
                                                const unsigned short* __restrict__ AB,
                                                float* __restrict__ y) {
    int bh = blockIdx.x >> 2, qtr = blockIdx.x & 3;
    __shared__ unsigned short ABl[128 * S3PITCH];
    int t = threadIdx.x;
    int lane = t & 63, wave = t >> 6;
    int r = lane & 15, kb8 = lane >> 4;

    {   // load AB[bh] (128x64 bf16) into LDS, padded pitch
        const unsigned* src = (const unsigned*)(AB + (size_t)bh * 8192);
        #pragma unroll
        for (int i = 0; i < 16; ++i) {
            int idx = t + i * 256;             // u32 index over [128][32]
            int m = idx >> 5, op = idx & 31;
            ((unsigned*)ABl)[m * (S3PITCH / 2) + op] = src[idx];
        }
    }
    __syncthreads();

    s16x8 bfr[4][4];                           // [kstep][nsub]
    #pragma unroll
    for (int ks = 0; ks < 4; ++ks)
        #pragma unroll
        for (int ns = 0; ns < 4; ++ns) {
            s16x8 v;
            #pragma unroll
            for (int i = 0; i < 8; ++i) {
                int m = ks * 32 + kb8 * 8 + i;
                v[i] = (short)ABl[m * S3PITCH + ns * 16 + r];
            }
            bfr[ks][ns] = v;
        }

    for (int it = 0; it < 16; ++it) {
        int lbase = qtr * 1024 + it * 64 + wave * 16;
        s16x8 af[4];
        #pragma unroll
        for (int ks = 0; ks < 4; ++ks)
            af[ks] = *(const s16x8*)(Tt + (size_t)(lbase + r) * 128 + ks * 32 + kb8 * 8);
        f32x4 acc[4];
        #pragma unroll
        for (int ns = 0; ns < 4; ++ns) acc[ns] = (f32x4)0.f;
        #pragma unroll
        for (int ks = 0; ks < 4; ++ks)
            #pragma unroll
            for (int ns = 0; ns < 4; ++ns)
                acc[ns] = __builtin_amdgcn_mfma_f32_16x16x32_bf16(af[ks], bfr[ks][ns], acc[ns], 0, 0, 0);
        float* yb = y + ((size_t)bh * LTOT + lbase) * EDIM;
        #pragma unroll
        for (int ns = 0; ns < 4; ++ns)
            #pragma unroll
            for (int g = 0; g < 4; ++g)
                yb[(kb8 * 4 + g) * EDIM + ns * 16 + r] = acc[ns][g];
    }
}

extern "C" void kernel_launch(void* const* d_in, const int* in_sizes, int n_in,
                              void* d_out, int out_size, void* d_ws, size_t ws_size,
                              hipStream_t stream) {
    const float* x     = (const float*)d_in[0];
    const float* w     = (const float*)d_in[1];
    const int*   index = (const int*)d_in[2];
    float* y  = (float*)d_out;
    float* ws = (float*)d_ws;

    // ws layout (float offsets): Tm 1MB | Tt 1MB | Xp 33.5MB | AB 4MB  (~40MB total)
    unsigned short* Tm = (unsigned short*)ws;
    unsigned short* Tt = (unsigned short*)(ws + 262144);
    float*          Xp = ws + 524288;
    unsigned short* AB = (unsigned short*)(ws + 8912896);

    hipLaunchKernelGGL(k_tab_m,  dim3(NMODES), dim3(256), 0, stream, index, Tm);
    hipLaunchKernelGGL(k_tab_t,  dim3(1024),   dim3(256), 0, stream, index, Tt);
    hipLaunchKernelGGL(k_stage1, dim3(BH * 4), dim3(256), 0, stream, x, Tm, Xp);
    hipLaunchKernelGGL(k_stage2, dim3(BH / 2), dim3(512), 0, stream, Xp, (const float2*)w, index, AB);
    hipLaunchKernelGGL(k_stage3, dim3(BH * 4), dim3(256), 0, stream, Tt, AB, y);
}